// Round 20
// baseline (1563.362 us; speedup 1.0000x reference)
//
#include <hip/hip_runtime.h>
#include <math.h>

#define NGRAPH 512

typedef __attribute__((ext_vector_type(8))) __bf16 bf16x8;
typedef __attribute__((ext_vector_type(4))) float f32x4;

__device__ __forceinline__ unsigned short f2bf(float x) {
    unsigned int u = __float_as_uint(x);
    u = (u + 0x7fffu + ((u >> 16) & 1u)) >> 16;   // RNE
    return (unsigned short)u;
}
__device__ __forceinline__ float bf2f(unsigned short b) {
    return __uint_as_float(((unsigned int)b) << 16);
}

static inline unsigned grid_for(size_t n, int block = 256) {
    return (unsigned)((n + block - 1) / block);
}

__global__ void fill_i32(int* __restrict__ p, int v, size_t n) {
    size_t i = blockIdx.x * (size_t)blockDim.x + threadIdx.x;
    if (i < n) p[i] = v;
}

__global__ void fill_f32(float* __restrict__ p, float v, size_t n) {
    size_t i = blockIdx.x * (size_t)blockDim.x + threadIdx.x;
    if (i < n) p[i] = v;
}

__global__ void hist_kernel(const int* __restrict__ col, int E, int* __restrict__ cnt) {
    size_t i = blockIdx.x * (size_t)blockDim.x + threadIdx.x;
    if (i < (size_t)E) atomicAdd(&cnt[col[i]], 1);
}

// fp32 W[K][N] -> bf16 Wt[N][KPAD] (transposed, K-pad zeroed)
__global__ void wcvt_t(const float* __restrict__ in, unsigned short* __restrict__ out,
                       int K, int N, int KPAD) {
    int i = blockIdx.x * blockDim.x + threadIdx.x;
    if (i >= N * KPAD) return;
    int n = i / KPAD, k = i - n * KPAD;
    out[i] = (k < K) ? f2bf(in[(size_t)k * N + n]) : (unsigned short)0;
}

// ---- scan over pos[] (in-place, exclusive; pass1 also emits dinv; pass3 writes pos[n]=E) ----
__global__ void scan_pass1(const int* __restrict__ in, int* __restrict__ bsum,
                           float* __restrict__ dinv, int n) {
    __shared__ int sdata[256];
    int tid = threadIdx.x;
    int i = blockIdx.x * 256 + tid;
    int v = (i < n) ? in[i] : 0;
    if (i < n) dinv[i] = 1.0f / sqrtf((float)v + 1.0f);   // +1 = self loop
    sdata[tid] = v;
    __syncthreads();
    for (int s = 128; s > 0; s >>= 1) {
        if (tid < s) sdata[tid] += sdata[tid + s];
        __syncthreads();
    }
    if (tid == 0) bsum[blockIdx.x] = sdata[0];
}

__global__ void scan_pass2(int* __restrict__ bsum, int nb) {
    __shared__ int s[1024];
    int tid = threadIdx.x;
    int v = (tid < nb) ? bsum[tid] : 0;
    s[tid] = v;
    __syncthreads();
    for (int ofs = 1; ofs < 1024; ofs <<= 1) {
        int t = (tid >= ofs) ? s[tid - ofs] : 0;
        __syncthreads();
        s[tid] += t;
        __syncthreads();
    }
    if (tid < nb) bsum[tid] = s[tid] - v;   // exclusive prefix
}

__global__ void scan_pass3(int* __restrict__ pos, const int* __restrict__ bsum, int n) {
    __shared__ int sdata[256];
    int tid = threadIdx.x;
    int i = blockIdx.x * 256 + tid;
    int v = (i < n) ? pos[i] : 0;
    sdata[tid] = v;
    __syncthreads();
    for (int ofs = 1; ofs < 256; ofs <<= 1) {
        int t = (tid >= ofs) ? sdata[tid - ofs] : 0;
        __syncthreads();
        sdata[tid] += t;
        __syncthreads();
    }
    if (i < n) pos[i] = sdata[tid] - v + bsum[blockIdx.x];
    if (i == n - 1) pos[n] = sdata[tid] + bsum[blockIdx.x];   // total = E
}

// bucket bump pointers: bump[b] = pos[b*SPB] (start of bucket's CSR range)
__global__ void bump_init(const int* __restrict__ pos, int* __restrict__ bump, int NB, int SPB) {
    int b = blockIdx.x * blockDim.x + threadIdx.x;
    if (b < NB) bump[b] = pos[b * SPB];
}

// Pass B: append each edge (with coef) to its destination bucket region.
// Bucket writes are sequential (bump pointers) -> dense lines, ~1x write amp.
__global__ void bin_fill(const int* __restrict__ row, const int* __restrict__ col,
                         const float* __restrict__ attr, const float* __restrict__ dinv,
                         int* __restrict__ bump, int4* __restrict__ tmp, int E, int SPB) {
    size_t i = blockIdx.x * (size_t)blockDim.x + threadIdx.x;
    if (i >= (size_t)E) return;
    int r = row[i], c = col[i];
    int slot = atomicAdd(&bump[c / SPB], 1);
    tmp[slot] = make_int4(r, c, __float_as_int(dinv[r] * attr[i] * dinv[c]), 0);
}

// Pass C: one block per bucket; scatter within the bucket's contiguous CSR
// window using per-node LDS bump counters (window stays L2-hot).
template <int SPB>
__global__ __launch_bounds__(256) void csr_place(const int* __restrict__ pos,
                                                 const int4* __restrict__ tmp,
                                                 int2* __restrict__ rcp, int N) {
    __shared__ int bl[SPB];
    int b = blockIdx.x;
    int lo = b * SPB;
    int hi = lo + SPB; if (hi > N) hi = N;
    int nn = hi - lo;
    for (int i = threadIdx.x; i < nn; i += 256) bl[i] = pos[lo + i];
    __syncthreads();
    int base = pos[lo];
    int cnt = pos[hi] - base;
    for (int idx = threadIdx.x; idx < cnt; idx += 256) {
        int4 t = tmp[base + idx];
        int ls = atomicAdd(&bl[t.y - lo], 1);
        rcp[ls] = make_int2(t.x, t.z);
    }
}

// CSR gather-aggregate -> bf16 output, K padded to LDO (pad zeroed), packed CSR.
// pos is exclusive prefix with pos[N]=E: segment = [pos[gid], pos[gid+1]).
template <int V, int LPG, int F, int LDI, int LDO, bool INBF>
__global__ void gather_bf(const int* __restrict__ pos, const int2* __restrict__ rcp,
                          const void* __restrict__ Xv, const float* __restrict__ dinv,
                          unsigned short* __restrict__ AGG, int N) {
    constexpr int gpb = 256 / LPG;
    int grp = threadIdx.x / LPG;
    if (grp >= gpb) return;
    int gid = blockIdx.x * gpb + grp;
    int lane = threadIdx.x - grp * LPG;
    if (gid >= N) return;

    auto load_row = [&](int r, float* dst) {
        if (INBF) {
            const unsigned short* X = (const unsigned short*)Xv;
            if (V == 2) {
                unsigned int u = *reinterpret_cast<const unsigned int*>(X + (size_t)r * LDI + lane * 2);
                dst[0] = bf2f((unsigned short)(u & 0xffffu));
                dst[1] = bf2f((unsigned short)(u >> 16));
            } else {
                uint2 u = *reinterpret_cast<const uint2*>(X + (size_t)r * LDI + lane * 4);
                dst[0] = bf2f((unsigned short)(u.x & 0xffffu));
                dst[1] = bf2f((unsigned short)(u.x >> 16));
                dst[2] = bf2f((unsigned short)(u.y & 0xffffu));
                dst[3] = bf2f((unsigned short)(u.y >> 16));
            }
        } else {
            const float* X = (const float*)Xv;
            if (V == 2) {
                float2 u = *reinterpret_cast<const float2*>(X + (size_t)r * LDI + lane * 2);
                dst[0] = u.x; dst[1] = u.y;
            } else {
                float4 u = *reinterpret_cast<const float4*>(X + (size_t)r * LDI + lane * 4);
                dst[0] = u.x; dst[1] = u.y; dst[2] = u.z; dst[3] = u.w;
            }
        }
    };

    int start = pos[gid];
    int end = pos[gid + 1];
    float s = dinv[gid];
    float s2 = s * s;
    float acc[V];
    load_row(gid, acc);
#pragma unroll
    for (int j = 0; j < V; ++j) acc[j] *= s2;
    int t = start;
    for (; t + 4 <= end; t += 4) {
        int2 e0 = rcp[t], e1 = rcp[t + 1], e2 = rcp[t + 2], e3 = rcp[t + 3];
        float c0 = __int_as_float(e0.y), c1 = __int_as_float(e1.y);
        float c2 = __int_as_float(e2.y), c3 = __int_as_float(e3.y);
        float h0[V], h1[V], h2[V], h3[V];
        load_row(e0.x, h0); load_row(e1.x, h1); load_row(e2.x, h2); load_row(e3.x, h3);
#pragma unroll
        for (int j = 0; j < V; ++j) {
            float v = fmaf(c0, h0[j], acc[j]);
            v = fmaf(c1, h1[j], v);
            v = fmaf(c2, h2[j], v);
            acc[j] = fmaf(c3, h3[j], v);
        }
    }
    for (; t < end; ++t) {
        int2 e = rcp[t];
        float cf = __int_as_float(e.y);
        float h[V];
        load_row(e.x, h);
#pragma unroll
        for (int j = 0; j < V; ++j) acc[j] = fmaf(cf, h[j], acc[j]);
    }
    unsigned short* op = AGG + (size_t)gid * LDO + lane * V;
    if (V == 2) {
        unsigned int p = (unsigned int)f2bf(acc[0]) | ((unsigned int)f2bf(acc[1]) << 16);
        *reinterpret_cast<unsigned int*>(op) = p;
    } else {
        uint2 p;
        p.x = (unsigned int)f2bf(acc[0]) | ((unsigned int)f2bf(acc[1]) << 16);
        p.y = (unsigned int)f2bf(acc[2]) | ((unsigned int)f2bf(acc[3]) << 16);
        *reinterpret_cast<uint2*>(op) = p;
    }
    constexpr int PAD = LDO - F;
#pragma unroll
    for (int p = lane; p < PAD; p += LPG) AGG[(size_t)gid * LDO + F + p] = 0;
}

// bf16 MFMA GEMM: A panel in LDS with XOR chunk swizzle; B direct from global
// pre-transposed Wt[N][KPAD]. (R17 proven)
template <int KPAD, int BN>
__global__ __launch_bounds__(256) void tgemm_mfma(
        const unsigned short* __restrict__ A, const unsigned short* __restrict__ Wt,
        unsigned short* __restrict__ C, int M, int N, int ldc) {
    constexpr int CH = KPAD / 8;
    constexpr int KSTEPS = KPAD / 32;
    constexpr int NI = (BN / 2) / 16;
    __shared__ unsigned short As[128 * KPAD];
    const int tid = threadIdx.x;
    const int m0 = blockIdx.y * 128;
    const int n0 = blockIdx.x * BN;

    for (int idx = tid; idx < 128 * CH; idx += 256) {
        int m = idx / CH;
        int c = idx - m * CH;
        int gm = m0 + m;
        uint4 v = make_uint4(0u, 0u, 0u, 0u);
        if (gm < M) v = *reinterpret_cast<const uint4*>(A + (size_t)gm * KPAD + c * 8);
        int cs = c ^ (m & 7);
        *reinterpret_cast<uint4*>(&As[m * KPAD + cs * 8]) = v;
    }
    __syncthreads();

    const int wid = tid >> 6;
    const int l = tid & 63;
    const int wm = wid >> 1, wn = wid & 1;
    const int lr = l & 15, lg = l >> 4;

    f32x4 acc[4][NI];
#pragma unroll
    for (int i = 0; i < 4; ++i)
#pragma unroll
        for (int j = 0; j < NI; ++j) acc[i][j] = (f32x4){0.f, 0.f, 0.f, 0.f};

    for (int ks = 0; ks < KSTEPS; ++ks) {
        bf16x8 a[4], b[NI];
#pragma unroll
        for (int mi = 0; mi < 4; ++mi) {
            int row = wm * 64 + mi * 16 + lr;
            int cs = (ks * 4 + lg) ^ (row & 7);
            a[mi] = *reinterpret_cast<const bf16x8*>(&As[row * KPAD + cs * 8]);
        }
#pragma unroll
        for (int ni = 0; ni < NI; ++ni) {
            int gn = n0 + wn * (BN / 2) + ni * 16 + lr;
            int gns = (gn < N) ? gn : (N - 1);
            b[ni] = *reinterpret_cast<const bf16x8*>(
                &Wt[(size_t)gns * KPAD + ks * 32 + lg * 8]);
        }
#pragma unroll
        for (int mi = 0; mi < 4; ++mi)
#pragma unroll
            for (int ni = 0; ni < NI; ++ni)
                acc[mi][ni] = __builtin_amdgcn_mfma_f32_16x16x32_bf16(
                    a[mi], b[ni], acc[mi][ni], 0, 0, 0);
    }

#pragma unroll
    for (int mi = 0; mi < 4; ++mi) {
#pragma unroll
        for (int ni = 0; ni < NI; ++ni) {
#pragma unroll
            for (int j = 0; j < 4; ++j) {
                int gm = m0 + wm * 64 + mi * 16 + lg * 4 + j;
                int gn = n0 + wn * (BN / 2) + ni * 16 + lr;
                if (gm < M && gn < N)
                    C[(size_t)gm * ldc + gn] = f2bf(fmaxf(acc[mi][ni][j], 0.0f));
            }
        }
    }
}

// Partial mean-pool over bf16 rows (R18 proven)
template <int F2, int SUB>
__global__ void pool_part_bf(const unsigned short* __restrict__ X, const int* __restrict__ batch,
                             float* __restrict__ pool, int N, int PB) {
    int g = blockIdx.x / PB;
    int st = blockIdx.x - g * PB;
    int tid = threadIdx.x;
    int p = tid % F2;
    int sub = tid / F2;
    if (sub >= SUB) return;
    int lo = 0, hi = N;
    while (lo < hi) { int mid = (lo + hi) >> 1; if (batch[mid] < g) lo = mid + 1; else hi = mid; }
    int s0 = lo;
    hi = N;
    while (lo < hi) { int mid = (lo + hi) >> 1; if (batch[mid] < g + 1) lo = mid + 1; else hi = mid; }
    int s1 = lo;
    const int F = 2 * F2;
    int stride = PB * SUB;
    float a0 = 0.0f, a1 = 0.0f;
    for (int n = s0 + st * SUB + sub; n < s1; n += stride) {
        unsigned int u = *reinterpret_cast<const unsigned int*>(X + (size_t)n * F + 2 * p);
        a0 += fmaxf(bf2f((unsigned short)(u & 0xffffu)), 0.0f);
        a1 += fmaxf(bf2f((unsigned short)(u >> 16)), 0.0f);
    }
    atomicAdd(&pool[(size_t)g * F + 2 * p], a0);
    atomicAdd(&pool[(size_t)g * F + 2 * p + 1], a1);
}

// divide pool[g][:] by segment count
__global__ void pool_div_g(float* __restrict__ pool, const int* __restrict__ batch,
                           int N, int F) {
    int g = blockIdx.x;
    int lo = 0, hi = N;
    while (lo < hi) { int mid = (lo + hi) >> 1; if (batch[mid] < g) lo = mid + 1; else hi = mid; }
    int s0 = lo;
    hi = N;
    while (lo < hi) { int mid = (lo + hi) >> 1; if (batch[mid] < g + 1) lo = mid + 1; else hi = mid; }
    int c = lo - s0;
    float inv = 1.0f / (float)(c > 0 ? c : 1);
    for (int f = threadIdx.x; f < F; f += blockDim.x)
        pool[(size_t)g * F + f] *= inv;
}

// Fused gather+GEMM (protein), bf16 in/out, fp32 math. pos exclusive w/ pos[N].
template <int K, int NOUT, bool INBF>
__global__ __launch_bounds__(64 * (K / 4)) void fused_conv_bf(
        const int* __restrict__ pos, const int2* __restrict__ rcp,
        const void* __restrict__ Xv, const float* __restrict__ dinv,
        const float* __restrict__ W, unsigned short* __restrict__ Y, int N) {
    constexpr int LPG = K / 4;
    constexpr int NTHREADS = 64 * LPG;
    __shared__ float Ws[K][NOUT];
    __shared__ float Ag[64][K + 8];
    const int tid = threadIdx.x;
    const int nid0 = blockIdx.x * 64;

    for (int i = tid; i < K * NOUT; i += NTHREADS) Ws[i / NOUT][i % NOUT] = W[i];

    int grp = tid / LPG, lane = tid % LPG;
    int gid = nid0 + grp;

    auto load_row = [&](int r, float* dst) {
        if (INBF) {
            const unsigned short* X = (const unsigned short*)Xv;
            uint2 u = *reinterpret_cast<const uint2*>(X + (size_t)r * K + lane * 4);
            dst[0] = bf2f((unsigned short)(u.x & 0xffffu));
            dst[1] = bf2f((unsigned short)(u.x >> 16));
            dst[2] = bf2f((unsigned short)(u.y & 0xffffu));
            dst[3] = bf2f((unsigned short)(u.y >> 16));
        } else {
            const float* X = (const float*)Xv;
            float4 u = *reinterpret_cast<const float4*>(X + (size_t)r * K + lane * 4);
            dst[0] = u.x; dst[1] = u.y; dst[2] = u.z; dst[3] = u.w;
        }
    };

    if (gid < N) {
        int start = pos[gid];
        int end = pos[gid + 1];
        float s = dinv[gid];
        float s2 = s * s;
        float acc[4];
        load_row(gid, acc);
#pragma unroll
        for (int j = 0; j < 4; ++j) acc[j] *= s2;
        int t = start;
        for (; t + 4 <= end; t += 4) {
            int2 e0 = rcp[t], e1 = rcp[t + 1], e2 = rcp[t + 2], e3 = rcp[t + 3];
            float c0 = __int_as_float(e0.y), c1 = __int_as_float(e1.y);
            float c2 = __int_as_float(e2.y), c3 = __int_as_float(e3.y);
            float h0[4], h1[4], h2[4], h3[4];
            load_row(e0.x, h0); load_row(e1.x, h1); load_row(e2.x, h2); load_row(e3.x, h3);
#pragma unroll
            for (int j = 0; j < 4; ++j) {
                float v = fmaf(c0, h0[j], acc[j]);
                v = fmaf(c1, h1[j], v);
                v = fmaf(c2, h2[j], v);
                acc[j] = fmaf(c3, h3[j], v);
            }
        }
        for (; t < end; ++t) {
            int2 e = rcp[t];
            float cf = __int_as_float(e.y);
            float h[4];
            load_row(e.x, h);
#pragma unroll
            for (int j = 0; j < 4; ++j) acc[j] = fmaf(cf, h[j], acc[j]);
        }
#pragma unroll
        for (int j = 0; j < 4; ++j) Ag[grp][lane * 4 + j] = acc[j];
    }
    __syncthreads();

    for (int idx = tid; idx < 64 * NOUT; idx += NTHREADS) {
        int nl = idx / NOUT, n = idx % NOUT;
        int g = nid0 + nl;
        if (g < N) {
            float acc = 0.0f;
#pragma unroll
            for (int k = 0; k < K; ++k) acc = fmaf(Ag[nl][k], Ws[k][n], acc);
            Y[(size_t)g * NOUT + n] = f2bf(fmaxf(acc, 0.0f));
        }
    }
}

// Skinny MLP GEMM, 4-graph batched (R15 proven)
template <bool RELU_OUT>
__global__ __launch_bounds__(256) void skinny_gemm4(
        const float* __restrict__ A, const float* __restrict__ W,
        const float* __restrict__ bias, float* __restrict__ C,
        int K, int M, int ldc, int coff) {
    __shared__ float As[4][1024];
    __shared__ float red[4][64][4];
    const int tid = threadIdx.x;
    const int m_l = tid & 63;
    const int q = tid >> 6;
    const int g0 = blockIdx.y * 4;
    const int m0 = blockIdx.x * 64;

    for (int idx = tid; idx < 4 * K; idx += 256)
        As[idx / K][idx % K] = A[(size_t)(g0 + idx / K) * K + idx % K];
    __syncthreads();

    const int Kq = (K + 3) >> 2;
    const int ks = q * Kq;
    const int ke = (ks + Kq < K) ? ks + Kq : K;
    const int m = m0 + m_l;
    float acc[4] = {0.0f, 0.0f, 0.0f, 0.0f};
    if (m < M) {
        for (int k = ks; k < ke; ++k) {
            float w = W[(size_t)k * M + m];
            acc[0] = fmaf(As[0][k], w, acc[0]);
            acc[1] = fmaf(As[1][k], w, acc[1]);
            acc[2] = fmaf(As[2][k], w, acc[2]);
            acc[3] = fmaf(As[3][k], w, acc[3]);
        }
    }
#pragma unroll
    for (int g = 0; g < 4; ++g) red[q][m_l][g] = acc[g];
    __syncthreads();
    if (q == 0 && m < M) {
        float b = bias[m];
#pragma unroll
        for (int g = 0; g < 4; ++g) {
            float v = red[0][m_l][g] + red[1][m_l][g] + red[2][m_l][g] + red[3][m_l][g] + b;
            if (RELU_OUT) v = fmaxf(v, 0.0f);
            C[(size_t)(g0 + g) * ldc + coff + m] = v;
        }
    }
}

__global__ void final_kernel(const float* __restrict__ A, const float* __restrict__ w,
                             const float* __restrict__ b, float* __restrict__ out, int K) {
    int wave = (blockIdx.x * blockDim.x + threadIdx.x) >> 6;
    int lane = threadIdx.x & 63;
    if (wave >= NGRAPH) return;
    const float* ar = A + (size_t)wave * K;
    float acc = 0.0f;
    for (int k = lane; k < K; k += 64) acc = fmaf(ar[k], w[k], acc);
#pragma unroll
    for (int s = 32; s > 0; s >>= 1) acc += __shfl_down(acc, s, 64);
    if (lane == 0) out[wave] = acc + b[0];
}

// build CSR: pos = exclusive prefix (pos[N]=E); bucketed dense placement.
static void build_csr(const int* row, const int* col, const float* attr,
                      int N, int E, float* dinv, int* pos, int2* rcp,
                      int* bsum, int* bump, int4* tmp, hipStream_t stream) {
    const int B = 256;
    const int SPB = 256;
    int nb = (N + 255) / 256;
    int NB = (N + SPB - 1) / SPB;
    fill_i32<<<grid_for(N), B, 0, stream>>>(pos, 0, (size_t)N);
    hist_kernel<<<grid_for(E), B, 0, stream>>>(col, E, pos);
    scan_pass1<<<nb, B, 0, stream>>>(pos, bsum, dinv, N);
    scan_pass2<<<1, 1024, 0, stream>>>(bsum, nb);
    scan_pass3<<<nb, B, 0, stream>>>(pos, bsum, N);
    bump_init<<<grid_for(NB), B, 0, stream>>>(pos, bump, NB, SPB);
    bin_fill<<<grid_for(E), B, 0, stream>>>(row, col, attr, dinv, bump, tmp, E, SPB);
    csr_place<256><<<NB, B, 0, stream>>>(pos, tmp, rcp, N);
}

extern "C" void kernel_launch(void* const* d_in, const int* in_sizes, int n_in,
                              void* d_out, int out_size, void* d_ws, size_t ws_size,
                              hipStream_t stream) {
    const float* drug_x  = (const float*)d_in[0];
    const int*   d_ei    = (const int*)d_in[1];
    const float* d_ea    = (const float*)d_in[2];
    const int*   d_batch = (const int*)d_in[3];
    const float* prot_x  = (const float*)d_in[4];
    const int*   p_ei    = (const int*)d_in[5];
    const float* p_ea    = (const float*)d_in[6];
    const int*   p_batch = (const int*)d_in[7];
    const float* dW1 = (const float*)d_in[8];
    const float* dW2 = (const float*)d_in[9];
    const float* dW3 = (const float*)d_in[10];
    const float* dL1_w = (const float*)d_in[11];
    const float* dL1_b = (const float*)d_in[12];
    const float* dL2_w = (const float*)d_in[13];
    const float* dL2_b = (const float*)d_in[14];
    const float* pW1 = (const float*)d_in[15];
    const float* pW2 = (const float*)d_in[16];
    const float* pW3 = (const float*)d_in[17];
    const float* pL1_w = (const float*)d_in[18];
    const float* pL1_b = (const float*)d_in[19];
    const float* pL2_w = (const float*)d_in[20];
    const float* pL2_b = (const float*)d_in[21];
    const float* fW1 = (const float*)d_in[22];
    const float* fb1 = (const float*)d_in[23];
    const float* fW2 = (const float*)d_in[24];
    const float* fb2 = (const float*)d_in[25];
    const float* fW3 = (const float*)d_in[26];
    const float* fb3 = (const float*)d_in[27];
    float* out = (float*)d_out;

    const int Nd = in_sizes[0] / 78;
    const int Ed = in_sizes[1] / 2;
    const int Np = in_sizes[4] / 20;
    const int Ep = in_sizes[5] / 2;
    const int* d_row = d_ei;
    const int* d_col = d_ei + Ed;
    const int* p_row = p_ei;
    const int* p_col = p_ei + Ep;

    // ---- workspace layout (floats); proven-safe total ----
    float* ws = (float*)d_ws;
    size_t off = 0;
    auto align256 = [](size_t n) -> size_t { return (n + 255) & ~(size_t)255; };
    auto take = [&](size_t n) -> float* {
        float* p = ws + off;
        off += align256(n);
        return p;
    };
    float* B1      = take((size_t)Nd * 312);   // conv outputs (bf16 views)
    float* B2      = take((size_t)Nd * 312);   // aggregates (bf16 views) + bin tmp tail
    float* dinv_d  = take((size_t)Nd);
    float* dinv_p  = take((size_t)Np);
    float* pool    = take((size_t)NGRAPH * 312);
    float* t1      = take((size_t)NGRAPH * 1024);
    float* Cbuf    = take((size_t)NGRAPH * 128);
    float* f2buf   = take((size_t)NGRAPH * 512);
    int*   bsum    = (int*)take(1056);
    int*   bump    = (int*)take(1024);
    int*   pos_d   = (int*)take((size_t)Nd + 1);
    int2*  rcp_d   = (int2*)take((size_t)Ed * 2);
    unsigned short* Wt1 = (unsigned short*)take((78 * 128) / 2);
    unsigned short* Wt2 = (unsigned short*)take((156 * 128) / 2);
    unsigned short* Wt3 = (unsigned short*)take((312 * 192) / 2);
    // bin tmp (int4/edge) in the dead tail of B2 (drug aggregates use <= Nd*96 floats)
    int4*  tmp     = (int4*)(B2 + align256((size_t)Nd * 96));
    // protein CSR in the dead tail of B1 (protein bf16 outputs use <= Np*40 floats)
    size_t tail = align256((size_t)Np * 80);
    int*   pos_p   = (int*)(B1 + tail);
    int2*  rcp_p   = (int2*)(B1 + tail + align256((size_t)Np + 1));
    (void)ws_size;

    unsigned short* B1u = (unsigned short*)B1;
    unsigned short* B2u = (unsigned short*)B2;

    const int B = 256;
    auto gblocks = [](int n, int gpb) -> unsigned { return (unsigned)((n + gpb - 1) / gpb); };
    auto mgrid = [](int M, int N, int BN) -> dim3 {
        return dim3((unsigned)((N + BN - 1) / BN), (unsigned)((M + 127) / 128));
    };

    // ================= drug branch (bf16 MFMA): 78 -> 78 -> 156 -> 312 =================
    build_csr(d_row, d_col, d_ea, Nd, Ed, dinv_d, pos_d, rcp_d, bsum, bump, tmp, stream);
    wcvt_t<<<grid_for(78 * 128), B, 0, stream>>>(dW1, Wt1, 78, 78, 128);
    wcvt_t<<<grid_for(156 * 128), B, 0, stream>>>(dW2, Wt2, 78, 156, 128);
    wcvt_t<<<grid_for(312 * 192), B, 0, stream>>>(dW3, Wt3, 156, 312, 192);

    gather_bf<2, 39, 78, 78, 128, false><<<gblocks(Nd, 256 / 39), B, 0, stream>>>(
        pos_d, rcp_d, drug_x, dinv_d, B2u, Nd);
    tgemm_mfma<128, 64><<<mgrid(Nd, 78, 64), B, 0, stream>>>(B2u, Wt1, B1u, Nd, 78, 80);

    gather_bf<2, 39, 78, 80, 128, true><<<gblocks(Nd, 256 / 39), B, 0, stream>>>(
        pos_d, rcp_d, B1u, dinv_d, B2u, Nd);
    tgemm_mfma<128, 64><<<mgrid(Nd, 156, 64), B, 0, stream>>>(B2u, Wt2, B1u, Nd, 156, 156);

    gather_bf<4, 39, 156, 156, 192, true><<<gblocks(Nd, 256 / 39), B, 0, stream>>>(
        pos_d, rcp_d, B1u, dinv_d, B2u, Nd);
    tgemm_mfma<192, 64><<<mgrid(Nd, 312, 64), B, 0, stream>>>(B2u, Wt3, B1u, Nd, 312, 312);

    fill_f32<<<grid_for((size_t)NGRAPH * 312), B, 0, stream>>>(pool, 0.0f, (size_t)NGRAPH * 312);
    pool_part_bf<156, 1><<<NGRAPH * 8, B, 0, stream>>>(B1u, d_batch, pool, Nd, 8);
    pool_div_g<<<NGRAPH, B, 0, stream>>>(pool, d_batch, Nd, 312);

    skinny_gemm4<true><<<dim3(16, NGRAPH / 4), B, 0, stream>>>(pool, dL1_w, dL1_b, t1, 312, 1024, 1024, 0);
    skinny_gemm4<true><<<dim3(1, NGRAPH / 4), B, 0, stream>>>(t1, dL2_w, dL2_b, Cbuf, 1024, 64, 128, 0);

    // ================= protein branch (bf16 fused): 20 -> 20 -> 40 -> 80 =================
    build_csr(p_row, p_col, p_ea, Np, Ep, dinv_p, pos_p, rcp_p, bsum, bump, tmp, stream);

    fused_conv_bf<20, 20, false><<<gblocks(Np, 64), 320, 0, stream>>>(
        pos_p, rcp_p, prot_x, dinv_p, pW1, B1u, Np);
    fused_conv_bf<20, 40, true><<<gblocks(Np, 64), 320, 0, stream>>>(
        pos_p, rcp_p, B1u, dinv_p, pW2, B2u, Np);
    fused_conv_bf<40, 80, true><<<gblocks(Np, 64), 640, 0, stream>>>(
        pos_p, rcp_p, B2u, dinv_p, pW3, B1u, Np);

    fill_f32<<<grid_for((size_t)NGRAPH * 80), B, 0, stream>>>(pool, 0.0f, (size_t)NGRAPH * 80);
    pool_part_bf<40, 6><<<NGRAPH * 8, B, 0, stream>>>(B1u, p_batch, pool, Np, 8);
    pool_div_g<<<NGRAPH, B, 0, stream>>>(pool, p_batch, Np, 80);

    skinny_gemm4<true><<<dim3(16, NGRAPH / 4), B, 0, stream>>>(pool, pL1_w, pL1_b, t1, 80, 1024, 1024, 0);
    skinny_gemm4<true><<<dim3(1, NGRAPH / 4), B, 0, stream>>>(t1, pL2_w, pL2_b, Cbuf, 1024, 64, 128, 64);

    // ================= head: 128 -> 1024 -> 512 -> 1 =================
    skinny_gemm4<true><<<dim3(16, NGRAPH / 4), B, 0, stream>>>(Cbuf, fW1, fb1, t1, 128, 1024, 1024, 0);
    skinny_gemm4<true><<<dim3(8, NGRAPH / 4), B, 0, stream>>>(t1, fW2, fb2, f2buf, 1024, 512, 512, 0);
    final_kernel<<<grid_for((size_t)NGRAPH * 64), B, 0, stream>>>(f2buf, fW3, fb3, out, 512);
}

// Round 21
// 1003.166 us; speedup vs baseline: 1.5584x; 1.5584x over previous
//
#include <hip/hip_runtime.h>
#include <math.h>

#define NGRAPH 512

typedef __attribute__((ext_vector_type(8))) __bf16 bf16x8;
typedef __attribute__((ext_vector_type(4))) float f32x4;

__device__ __forceinline__ unsigned short f2bf(float x) {
    unsigned int u = __float_as_uint(x);
    u = (u + 0x7fffu + ((u >> 16) & 1u)) >> 16;   // RNE
    return (unsigned short)u;
}
__device__ __forceinline__ float bf2f(unsigned short b) {
    return __uint_as_float(((unsigned int)b) << 16);
}

static inline unsigned grid_for(size_t n, int block = 256) {
    return (unsigned)((n + block - 1) / block);
}

__global__ void fill_i32(int* __restrict__ p, int v, size_t n) {
    size_t i = blockIdx.x * (size_t)blockDim.x + threadIdx.x;
    if (i < n) p[i] = v;
}

__global__ void fill_f32(float* __restrict__ p, float v, size_t n) {
    size_t i = blockIdx.x * (size_t)blockDim.x + threadIdx.x;
    if (i < n) p[i] = v;
}

__global__ void hist_kernel(const int* __restrict__ col, int E, int* __restrict__ cnt) {
    size_t i = blockIdx.x * (size_t)blockDim.x + threadIdx.x;
    if (i < (size_t)E) atomicAdd(&cnt[col[i]], 1);
}

// fp32 W[K][N] -> bf16 Wt[N][KPAD] (transposed, K-pad zeroed)
__global__ void wcvt_t(const float* __restrict__ in, unsigned short* __restrict__ out,
                       int K, int N, int KPAD) {
    int i = blockIdx.x * blockDim.x + threadIdx.x;
    if (i >= N * KPAD) return;
    int n = i / KPAD, k = i - n * KPAD;
    out[i] = (k < K) ? f2bf(in[(size_t)k * N + n]) : (unsigned short)0;
}

// ---- scan over pos[] (in-place); pass1 also emits dinv ----
__global__ void scan_pass1(const int* __restrict__ in, int* __restrict__ bsum,
                           float* __restrict__ dinv, int n) {
    __shared__ int sdata[256];
    int tid = threadIdx.x;
    int i = blockIdx.x * 256 + tid;
    int v = (i < n) ? in[i] : 0;
    if (i < n) dinv[i] = 1.0f / sqrtf((float)v + 1.0f);   // +1 = self loop
    sdata[tid] = v;
    __syncthreads();
    for (int s = 128; s > 0; s >>= 1) {
        if (tid < s) sdata[tid] += sdata[tid + s];
        __syncthreads();
    }
    if (tid == 0) bsum[blockIdx.x] = sdata[0];
}

__global__ void scan_pass2(int* __restrict__ bsum, int nb) {
    __shared__ int s[1024];
    int tid = threadIdx.x;
    int v = (tid < nb) ? bsum[tid] : 0;
    s[tid] = v;
    __syncthreads();
    for (int ofs = 1; ofs < 1024; ofs <<= 1) {
        int t = (tid >= ofs) ? s[tid - ofs] : 0;
        __syncthreads();
        s[tid] += t;
        __syncthreads();
    }
    if (tid < nb) bsum[tid] = s[tid] - v;   // exclusive prefix
}

__global__ void scan_pass3(int* __restrict__ pos, const int* __restrict__ bsum, int n) {
    __shared__ int sdata[256];
    int tid = threadIdx.x;
    int i = blockIdx.x * 256 + tid;
    int v = (i < n) ? pos[i] : 0;
    sdata[tid] = v;
    __syncthreads();
    for (int ofs = 1; ofs < 256; ofs <<= 1) {
        int t = (tid >= ofs) ? sdata[tid - ofs] : 0;
        __syncthreads();
        sdata[tid] += t;
        __syncthreads();
    }
    if (i < n) pos[i] = sdata[tid] - v + bsum[blockIdx.x];
}

// CSR fill, packed int2 {row, coef_bits}: one 8B scattered write per edge.
// (R19 proven; bucketed bin_fill variant regressed 4x on atomic contention — R20 post-mortem.)
__global__ void csr_fill(const int* __restrict__ row, const int* __restrict__ col,
                         const float* __restrict__ attr, const float* __restrict__ dinv,
                         int* __restrict__ pos, int2* __restrict__ rcp, int E) {
    size_t i = blockIdx.x * (size_t)blockDim.x + threadIdx.x;
    if (i >= (size_t)E) return;
    int r = row[i], c = col[i];
    int slot = atomicAdd(&pos[c], 1);
    rcp[slot] = make_int2(r, __float_as_int(dinv[r] * attr[i] * dinv[c]));
}

// CSR gather-aggregate -> bf16 output, K padded to LDO (pad zeroed), packed CSR.
// pos is inclusive-end: segment = [gid? pos[gid-1]:0, pos[gid]).
template <int V, int LPG, int F, int LDI, int LDO, bool INBF>
__global__ void gather_bf(const int* __restrict__ pos, const int2* __restrict__ rcp,
                          const void* __restrict__ Xv, const float* __restrict__ dinv,
                          unsigned short* __restrict__ AGG, int N) {
    constexpr int gpb = 256 / LPG;
    int grp = threadIdx.x / LPG;
    if (grp >= gpb) return;
    int gid = blockIdx.x * gpb + grp;
    int lane = threadIdx.x - grp * LPG;
    if (gid >= N) return;

    auto load_row = [&](int r, float* dst) {
        if (INBF) {
            const unsigned short* X = (const unsigned short*)Xv;
            if (V == 2) {
                unsigned int u = *reinterpret_cast<const unsigned int*>(X + (size_t)r * LDI + lane * 2);
                dst[0] = bf2f((unsigned short)(u & 0xffffu));
                dst[1] = bf2f((unsigned short)(u >> 16));
            } else {
                uint2 u = *reinterpret_cast<const uint2*>(X + (size_t)r * LDI + lane * 4);
                dst[0] = bf2f((unsigned short)(u.x & 0xffffu));
                dst[1] = bf2f((unsigned short)(u.x >> 16));
                dst[2] = bf2f((unsigned short)(u.y & 0xffffu));
                dst[3] = bf2f((unsigned short)(u.y >> 16));
            }
        } else {
            const float* X = (const float*)Xv;
            if (V == 2) {
                float2 u = *reinterpret_cast<const float2*>(X + (size_t)r * LDI + lane * 2);
                dst[0] = u.x; dst[1] = u.y;
            } else {
                float4 u = *reinterpret_cast<const float4*>(X + (size_t)r * LDI + lane * 4);
                dst[0] = u.x; dst[1] = u.y; dst[2] = u.z; dst[3] = u.w;
            }
        }
    };

    int start = (gid == 0) ? 0 : pos[gid - 1];
    int end = pos[gid];
    float s = dinv[gid];
    float s2 = s * s;
    float acc[V];
    load_row(gid, acc);
#pragma unroll
    for (int j = 0; j < V; ++j) acc[j] *= s2;
    int t = start;
    for (; t + 4 <= end; t += 4) {
        int2 e0 = rcp[t], e1 = rcp[t + 1], e2 = rcp[t + 2], e3 = rcp[t + 3];
        float c0 = __int_as_float(e0.y), c1 = __int_as_float(e1.y);
        float c2 = __int_as_float(e2.y), c3 = __int_as_float(e3.y);
        float h0[V], h1[V], h2[V], h3[V];
        load_row(e0.x, h0); load_row(e1.x, h1); load_row(e2.x, h2); load_row(e3.x, h3);
#pragma unroll
        for (int j = 0; j < V; ++j) {
            float v = fmaf(c0, h0[j], acc[j]);
            v = fmaf(c1, h1[j], v);
            v = fmaf(c2, h2[j], v);
            acc[j] = fmaf(c3, h3[j], v);
        }
    }
    for (; t < end; ++t) {
        int2 e = rcp[t];
        float cf = __int_as_float(e.y);
        float h[V];
        load_row(e.x, h);
#pragma unroll
        for (int j = 0; j < V; ++j) acc[j] = fmaf(cf, h[j], acc[j]);
    }
    unsigned short* op = AGG + (size_t)gid * LDO + lane * V;
    if (V == 2) {
        unsigned int p = (unsigned int)f2bf(acc[0]) | ((unsigned int)f2bf(acc[1]) << 16);
        *reinterpret_cast<unsigned int*>(op) = p;
    } else {
        uint2 p;
        p.x = (unsigned int)f2bf(acc[0]) | ((unsigned int)f2bf(acc[1]) << 16);
        p.y = (unsigned int)f2bf(acc[2]) | ((unsigned int)f2bf(acc[3]) << 16);
        *reinterpret_cast<uint2*>(op) = p;
    }
    constexpr int PAD = LDO - F;
#pragma unroll
    for (int p = lane; p < PAD; p += LPG) AGG[(size_t)gid * LDO + F + p] = 0;
}

// bf16 MFMA GEMM: A panel in LDS with XOR chunk swizzle; B direct from global
// pre-transposed Wt[N][KPAD]. (R17 proven)
template <int KPAD, int BN>
__global__ __launch_bounds__(256) void tgemm_mfma(
        const unsigned short* __restrict__ A, const unsigned short* __restrict__ Wt,
        unsigned short* __restrict__ C, int M, int N, int ldc) {
    constexpr int CH = KPAD / 8;
    constexpr int KSTEPS = KPAD / 32;
    constexpr int NI = (BN / 2) / 16;
    __shared__ unsigned short As[128 * KPAD];
    const int tid = threadIdx.x;
    const int m0 = blockIdx.y * 128;
    const int n0 = blockIdx.x * BN;

    for (int idx = tid; idx < 128 * CH; idx += 256) {
        int m = idx / CH;
        int c = idx - m * CH;
        int gm = m0 + m;
        uint4 v = make_uint4(0u, 0u, 0u, 0u);
        if (gm < M) v = *reinterpret_cast<const uint4*>(A + (size_t)gm * KPAD + c * 8);
        int cs = c ^ (m & 7);
        *reinterpret_cast<uint4*>(&As[m * KPAD + cs * 8]) = v;
    }
    __syncthreads();

    const int wid = tid >> 6;
    const int l = tid & 63;
    const int wm = wid >> 1, wn = wid & 1;
    const int lr = l & 15, lg = l >> 4;

    f32x4 acc[4][NI];
#pragma unroll
    for (int i = 0; i < 4; ++i)
#pragma unroll
        for (int j = 0; j < NI; ++j) acc[i][j] = (f32x4){0.f, 0.f, 0.f, 0.f};

    for (int ks = 0; ks < KSTEPS; ++ks) {
        bf16x8 a[4], b[NI];
#pragma unroll
        for (int mi = 0; mi < 4; ++mi) {
            int row = wm * 64 + mi * 16 + lr;
            int cs = (ks * 4 + lg) ^ (row & 7);
            a[mi] = *reinterpret_cast<const bf16x8*>(&As[row * KPAD + cs * 8]);
        }
#pragma unroll
        for (int ni = 0; ni < NI; ++ni) {
            int gn = n0 + wn * (BN / 2) + ni * 16 + lr;
            int gns = (gn < N) ? gn : (N - 1);
            b[ni] = *reinterpret_cast<const bf16x8*>(
                &Wt[(size_t)gns * KPAD + ks * 32 + lg * 8]);
        }
#pragma unroll
        for (int mi = 0; mi < 4; ++mi)
#pragma unroll
            for (int ni = 0; ni < NI; ++ni)
                acc[mi][ni] = __builtin_amdgcn_mfma_f32_16x16x32_bf16(
                    a[mi], b[ni], acc[mi][ni], 0, 0, 0);
    }

#pragma unroll
    for (int mi = 0; mi < 4; ++mi) {
#pragma unroll
        for (int ni = 0; ni < NI; ++ni) {
#pragma unroll
            for (int j = 0; j < 4; ++j) {
                int gm = m0 + wm * 64 + mi * 16 + lg * 4 + j;
                int gn = n0 + wn * (BN / 2) + ni * 16 + lr;
                if (gm < M && gn < N)
                    C[(size_t)gm * ldc + gn] = f2bf(fmaxf(acc[mi][ni][j], 0.0f));
            }
        }
    }
}

// Partial mean-pool over bf16 rows (R18 proven)
template <int F2, int SUB>
__global__ void pool_part_bf(const unsigned short* __restrict__ X, const int* __restrict__ batch,
                             float* __restrict__ pool, int N, int PB) {
    int g = blockIdx.x / PB;
    int st = blockIdx.x - g * PB;
    int tid = threadIdx.x;
    int p = tid % F2;
    int sub = tid / F2;
    if (sub >= SUB) return;
    int lo = 0, hi = N;
    while (lo < hi) { int mid = (lo + hi) >> 1; if (batch[mid] < g) lo = mid + 1; else hi = mid; }
    int s0 = lo;
    hi = N;
    while (lo < hi) { int mid = (lo + hi) >> 1; if (batch[mid] < g + 1) lo = mid + 1; else hi = mid; }
    int s1 = lo;
    const int F = 2 * F2;
    int stride = PB * SUB;
    float a0 = 0.0f, a1 = 0.0f;
    for (int n = s0 + st * SUB + sub; n < s1; n += stride) {
        unsigned int u = *reinterpret_cast<const unsigned int*>(X + (size_t)n * F + 2 * p);
        a0 += fmaxf(bf2f((unsigned short)(u & 0xffffu)), 0.0f);
        a1 += fmaxf(bf2f((unsigned short)(u >> 16)), 0.0f);
    }
    atomicAdd(&pool[(size_t)g * F + 2 * p], a0);
    atomicAdd(&pool[(size_t)g * F + 2 * p + 1], a1);
}

// divide pool[g][:] by segment count
__global__ void pool_div_g(float* __restrict__ pool, const int* __restrict__ batch,
                           int N, int F) {
    int g = blockIdx.x;
    int lo = 0, hi = N;
    while (lo < hi) { int mid = (lo + hi) >> 1; if (batch[mid] < g) lo = mid + 1; else hi = mid; }
    int s0 = lo;
    hi = N;
    while (lo < hi) { int mid = (lo + hi) >> 1; if (batch[mid] < g + 1) lo = mid + 1; else hi = mid; }
    int c = lo - s0;
    float inv = 1.0f / (float)(c > 0 ? c : 1);
    for (int f = threadIdx.x; f < F; f += blockDim.x)
        pool[(size_t)g * F + f] *= inv;
}

// Fused gather+GEMM (protein), bf16 in/out, fp32 math. pos inclusive-end.
template <int K, int NOUT, bool INBF>
__global__ __launch_bounds__(64 * (K / 4)) void fused_conv_bf(
        const int* __restrict__ pos, const int2* __restrict__ rcp,
        const void* __restrict__ Xv, const float* __restrict__ dinv,
        const float* __restrict__ W, unsigned short* __restrict__ Y, int N) {
    constexpr int LPG = K / 4;
    constexpr int NTHREADS = 64 * LPG;
    __shared__ float Ws[K][NOUT];
    __shared__ float Ag[64][K + 8];
    const int tid = threadIdx.x;
    const int nid0 = blockIdx.x * 64;

    for (int i = tid; i < K * NOUT; i += NTHREADS) Ws[i / NOUT][i % NOUT] = W[i];

    int grp = tid / LPG, lane = tid % LPG;
    int gid = nid0 + grp;

    auto load_row = [&](int r, float* dst) {
        if (INBF) {
            const unsigned short* X = (const unsigned short*)Xv;
            uint2 u = *reinterpret_cast<const uint2*>(X + (size_t)r * K + lane * 4);
            dst[0] = bf2f((unsigned short)(u.x & 0xffffu));
            dst[1] = bf2f((unsigned short)(u.x >> 16));
            dst[2] = bf2f((unsigned short)(u.y & 0xffffu));
            dst[3] = bf2f((unsigned short)(u.y >> 16));
        } else {
            const float* X = (const float*)Xv;
            float4 u = *reinterpret_cast<const float4*>(X + (size_t)r * K + lane * 4);
            dst[0] = u.x; dst[1] = u.y; dst[2] = u.z; dst[3] = u.w;
        }
    };

    if (gid < N) {
        int start = (gid == 0) ? 0 : pos[gid - 1];
        int end = pos[gid];
        float s = dinv[gid];
        float s2 = s * s;
        float acc[4];
        load_row(gid, acc);
#pragma unroll
        for (int j = 0; j < 4; ++j) acc[j] *= s2;
        int t = start;
        for (; t + 4 <= end; t += 4) {
            int2 e0 = rcp[t], e1 = rcp[t + 1], e2 = rcp[t + 2], e3 = rcp[t + 3];
            float c0 = __int_as_float(e0.y), c1 = __int_as_float(e1.y);
            float c2 = __int_as_float(e2.y), c3 = __int_as_float(e3.y);
            float h0[4], h1[4], h2[4], h3[4];
            load_row(e0.x, h0); load_row(e1.x, h1); load_row(e2.x, h2); load_row(e3.x, h3);
#pragma unroll
            for (int j = 0; j < 4; ++j) {
                float v = fmaf(c0, h0[j], acc[j]);
                v = fmaf(c1, h1[j], v);
                v = fmaf(c2, h2[j], v);
                acc[j] = fmaf(c3, h3[j], v);
            }
        }
        for (; t < end; ++t) {
            int2 e = rcp[t];
            float cf = __int_as_float(e.y);
            float h[4];
            load_row(e.x, h);
#pragma unroll
            for (int j = 0; j < 4; ++j) acc[j] = fmaf(cf, h[j], acc[j]);
        }
#pragma unroll
        for (int j = 0; j < 4; ++j) Ag[grp][lane * 4 + j] = acc[j];
    }
    __syncthreads();

    for (int idx = tid; idx < 64 * NOUT; idx += NTHREADS) {
        int nl = idx / NOUT, n = idx % NOUT;
        int g = nid0 + nl;
        if (g < N) {
            float acc = 0.0f;
#pragma unroll
            for (int k = 0; k < K; ++k) acc = fmaf(Ag[nl][k], Ws[k][n], acc);
            Y[(size_t)g * NOUT + n] = f2bf(fmaxf(acc, 0.0f));
        }
    }
}

// Skinny MLP GEMM, 4-graph batched (R15 proven)
template <bool RELU_OUT>
__global__ __launch_bounds__(256) void skinny_gemm4(
        const float* __restrict__ A, const float* __restrict__ W,
        const float* __restrict__ bias, float* __restrict__ C,
        int K, int M, int ldc, int coff) {
    __shared__ float As[4][1024];
    __shared__ float red[4][64][4];
    const int tid = threadIdx.x;
    const int m_l = tid & 63;
    const int q = tid >> 6;
    const int g0 = blockIdx.y * 4;
    const int m0 = blockIdx.x * 64;

    for (int idx = tid; idx < 4 * K; idx += 256)
        As[idx / K][idx % K] = A[(size_t)(g0 + idx / K) * K + idx % K];
    __syncthreads();

    const int Kq = (K + 3) >> 2;
    const int ks = q * Kq;
    const int ke = (ks + Kq < K) ? ks + Kq : K;
    const int m = m0 + m_l;
    float acc[4] = {0.0f, 0.0f, 0.0f, 0.0f};
    if (m < M) {
        for (int k = ks; k < ke; ++k) {
            float w = W[(size_t)k * M + m];
            acc[0] = fmaf(As[0][k], w, acc[0]);
            acc[1] = fmaf(As[1][k], w, acc[1]);
            acc[2] = fmaf(As[2][k], w, acc[2]);
            acc[3] = fmaf(As[3][k], w, acc[3]);
        }
    }
#pragma unroll
    for (int g = 0; g < 4; ++g) red[q][m_l][g] = acc[g];
    __syncthreads();
    if (q == 0 && m < M) {
        float b = bias[m];
#pragma unroll
        for (int g = 0; g < 4; ++g) {
            float v = red[0][m_l][g] + red[1][m_l][g] + red[2][m_l][g] + red[3][m_l][g] + b;
            if (RELU_OUT) v = fmaxf(v, 0.0f);
            C[(size_t)(g0 + g) * ldc + coff + m] = v;
        }
    }
}

__global__ void final_kernel(const float* __restrict__ A, const float* __restrict__ w,
                             const float* __restrict__ b, float* __restrict__ out, int K) {
    int wave = (blockIdx.x * blockDim.x + threadIdx.x) >> 6;
    int lane = threadIdx.x & 63;
    if (wave >= NGRAPH) return;
    const float* ar = A + (size_t)wave * K;
    float acc = 0.0f;
    for (int k = lane; k < K; k += 64) acc = fmaf(ar[k], w[k], acc);
#pragma unroll
    for (int s = 32; s > 0; s >>= 1) acc += __shfl_down(acc, s, 64);
    if (lane == 0) out[wave] = acc + b[0];
}

// build CSR (pos ends as inclusive-end array; packed int2 edges) — R19 proven
static void build_csr(const int* row, const int* col, const float* attr,
                      int N, int E, float* dinv, int* pos,
                      int2* rcp, int* bsum, hipStream_t stream) {
    const int B = 256;
    int nb = (N + 255) / 256;
    fill_i32<<<grid_for(N), B, 0, stream>>>(pos, 0, (size_t)N);
    hist_kernel<<<grid_for(E), B, 0, stream>>>(col, E, pos);
    scan_pass1<<<nb, B, 0, stream>>>(pos, bsum, dinv, N);
    scan_pass2<<<1, 1024, 0, stream>>>(bsum, nb);
    scan_pass3<<<nb, B, 0, stream>>>(pos, bsum, N);
    csr_fill<<<grid_for(E), B, 0, stream>>>(row, col, attr, dinv, pos, rcp, E);
}

extern "C" void kernel_launch(void* const* d_in, const int* in_sizes, int n_in,
                              void* d_out, int out_size, void* d_ws, size_t ws_size,
                              hipStream_t stream) {
    const float* drug_x  = (const float*)d_in[0];
    const int*   d_ei    = (const int*)d_in[1];
    const float* d_ea    = (const float*)d_in[2];
    const int*   d_batch = (const int*)d_in[3];
    const float* prot_x  = (const float*)d_in[4];
    const int*   p_ei    = (const int*)d_in[5];
    const float* p_ea    = (const float*)d_in[6];
    const int*   p_batch = (const int*)d_in[7];
    const float* dW1 = (const float*)d_in[8];
    const float* dW2 = (const float*)d_in[9];
    const float* dW3 = (const float*)d_in[10];
    const float* dL1_w = (const float*)d_in[11];
    const float* dL1_b = (const float*)d_in[12];
    const float* dL2_w = (const float*)d_in[13];
    const float* dL2_b = (const float*)d_in[14];
    const float* pW1 = (const float*)d_in[15];
    const float* pW2 = (const float*)d_in[16];
    const float* pW3 = (const float*)d_in[17];
    const float* pL1_w = (const float*)d_in[18];
    const float* pL1_b = (const float*)d_in[19];
    const float* pL2_w = (const float*)d_in[20];
    const float* pL2_b = (const float*)d_in[21];
    const float* fW1 = (const float*)d_in[22];
    const float* fb1 = (const float*)d_in[23];
    const float* fW2 = (const float*)d_in[24];
    const float* fb2 = (const float*)d_in[25];
    const float* fW3 = (const float*)d_in[26];
    const float* fb3 = (const float*)d_in[27];
    float* out = (float*)d_out;

    const int Nd = in_sizes[0] / 78;
    const int Ed = in_sizes[1] / 2;
    const int Np = in_sizes[4] / 20;
    const int Ep = in_sizes[5] / 2;
    const int* d_row = d_ei;
    const int* d_col = d_ei + Ed;
    const int* p_row = p_ei;
    const int* p_col = p_ei + Ep;

    // ---- workspace layout (floats); proven-safe total ----
    float* ws = (float*)d_ws;
    size_t off = 0;
    auto align256 = [](size_t n) -> size_t { return (n + 255) & ~(size_t)255; };
    auto take = [&](size_t n) -> float* {
        float* p = ws + off;
        off += align256(n);
        return p;
    };
    float* B1      = take((size_t)Nd * 312);   // conv outputs (bf16 views)
    float* B2      = take((size_t)Nd * 312);   // aggregates (bf16 views)
    float* dinv_d  = take((size_t)Nd);
    float* dinv_p  = take((size_t)Np);
    float* pool    = take((size_t)NGRAPH * 312);
    float* t1      = take((size_t)NGRAPH * 1024);
    float* Cbuf    = take((size_t)NGRAPH * 128);
    float* f2buf   = take((size_t)NGRAPH * 512);
    int*   bsum    = (int*)take(1056);
    int*   pos_d   = (int*)take((size_t)Nd);
    int2*  rcp_d   = (int2*)take((size_t)Ed * 2);
    unsigned short* Wt1 = (unsigned short*)take((78 * 128) / 2);
    unsigned short* Wt2 = (unsigned short*)take((156 * 128) / 2);
    unsigned short* Wt3 = (unsigned short*)take((312 * 192) / 2);
    // protein CSR in the dead tail of B1 (protein bf16 outputs use <= Np*40 floats)
    size_t tail = align256((size_t)Np * 80);
    int*   pos_p   = (int*)(B1 + tail);
    int2*  rcp_p   = (int2*)(B1 + tail + align256((size_t)Np));
    (void)ws_size;

    unsigned short* B1u = (unsigned short*)B1;
    unsigned short* B2u = (unsigned short*)B2;

    const int B = 256;
    auto gblocks = [](int n, int gpb) -> unsigned { return (unsigned)((n + gpb - 1) / gpb); };
    auto mgrid = [](int M, int N, int BN) -> dim3 {
        return dim3((unsigned)((N + BN - 1) / BN), (unsigned)((M + 127) / 128));
    };

    // ================= drug branch (bf16 MFMA): 78 -> 78 -> 156 -> 312 =================
    build_csr(d_row, d_col, d_ea, Nd, Ed, dinv_d, pos_d, rcp_d, bsum, stream);
    wcvt_t<<<grid_for(78 * 128), B, 0, stream>>>(dW1, Wt1, 78, 78, 128);
    wcvt_t<<<grid_for(156 * 128), B, 0, stream>>>(dW2, Wt2, 78, 156, 128);
    wcvt_t<<<grid_for(312 * 192), B, 0, stream>>>(dW3, Wt3, 156, 312, 192);

    gather_bf<2, 39, 78, 78, 128, false><<<gblocks(Nd, 256 / 39), B, 0, stream>>>(
        pos_d, rcp_d, drug_x, dinv_d, B2u, Nd);
    tgemm_mfma<128, 64><<<mgrid(Nd, 78, 64), B, 0, stream>>>(B2u, Wt1, B1u, Nd, 78, 80);

    gather_bf<2, 39, 78, 80, 128, true><<<gblocks(Nd, 256 / 39), B, 0, stream>>>(
        pos_d, rcp_d, B1u, dinv_d, B2u, Nd);
    tgemm_mfma<128, 64><<<mgrid(Nd, 156, 64), B, 0, stream>>>(B2u, Wt2, B1u, Nd, 156, 156);

    gather_bf<4, 39, 156, 156, 192, true><<<gblocks(Nd, 256 / 39), B, 0, stream>>>(
        pos_d, rcp_d, B1u, dinv_d, B2u, Nd);
    tgemm_mfma<192, 64><<<mgrid(Nd, 312, 64), B, 0, stream>>>(B2u, Wt3, B1u, Nd, 312, 312);

    fill_f32<<<grid_for((size_t)NGRAPH * 312), B, 0, stream>>>(pool, 0.0f, (size_t)NGRAPH * 312);
    pool_part_bf<156, 1><<<NGRAPH * 8, B, 0, stream>>>(B1u, d_batch, pool, Nd, 8);
    pool_div_g<<<NGRAPH, B, 0, stream>>>(pool, d_batch, Nd, 312);

    skinny_gemm4<true><<<dim3(16, NGRAPH / 4), B, 0, stream>>>(pool, dL1_w, dL1_b, t1, 312, 1024, 1024, 0);
    skinny_gemm4<true><<<dim3(1, NGRAPH / 4), B, 0, stream>>>(t1, dL2_w, dL2_b, Cbuf, 1024, 64, 128, 0);

    // ================= protein branch (bf16 fused): 20 -> 20 -> 40 -> 80 =================
    build_csr(p_row, p_col, p_ea, Np, Ep, dinv_p, pos_p, rcp_p, bsum, stream);

    fused_conv_bf<20, 20, false><<<gblocks(Np, 64), 320, 0, stream>>>(
        pos_p, rcp_p, prot_x, dinv_p, pW1, B1u, Np);
    fused_conv_bf<20, 40, true><<<gblocks(Np, 64), 320, 0, stream>>>(
        pos_p, rcp_p, B1u, dinv_p, pW2, B2u, Np);
    fused_conv_bf<40, 80, true><<<gblocks(Np, 64), 640, 0, stream>>>(
        pos_p, rcp_p, B2u, dinv_p, pW3, B1u, Np);

    fill_f32<<<grid_for((size_t)NGRAPH * 80), B, 0, stream>>>(pool, 0.0f, (size_t)NGRAPH * 80);
    pool_part_bf<40, 6><<<NGRAPH * 8, B, 0, stream>>>(B1u, p_batch, pool, Np, 8);
    pool_div_g<<<NGRAPH, B, 0, stream>>>(pool, p_batch, Np, 80);

    skinny_gemm4<true><<<dim3(16, NGRAPH / 4), B, 0, stream>>>(pool, pL1_w, pL1_b, t1, 80, 1024, 1024, 0);
    skinny_gemm4<true><<<dim3(1, NGRAPH / 4), B, 0, stream>>>(t1, pL2_w, pL2_b, Cbuf, 1024, 64, 128, 64);

    // ================= head: 128 -> 1024 -> 512 -> 1 =================
    skinny_gemm4<true><<<dim3(16, NGRAPH / 4), B, 0, stream>>>(Cbuf, fW1, fb1, t1, 128, 1024, 1024, 0);
    skinny_gemm4<true><<<dim3(8, NGRAPH / 4), B, 0, stream>>>(t1, fW2, fb2, f2buf, 1024, 512, 512, 0);
    final_kernel<<<grid_for((size_t)NGRAPH * 64), B, 0, stream>>>(f2buf, fW3, fb3, out, 512);
}